// Round 9
// baseline (300.097 us; speedup 1.0000x reference)
//
#include <hip/hip_runtime.h>

#define NB 4
#define NS 2048
#define ND 768
#define NH 12
#define NDH 64
#define XPITCH 72
#define SSCALE 0.18033688011112043f   // (1/sqrt(64)) * log2(e)

typedef __bf16 bf16x8 __attribute__((ext_vector_type(8)));
typedef float  f32x4  __attribute__((ext_vector_type(4)));
typedef unsigned int u32;

#define MFMA16(a, b, c) __builtin_amdgcn_mfma_f32_16x16x32_bf16(a, b, c, 0, 0, 0)

__device__ __forceinline__ u32 packbf(float a, float b) {
    u32 ua = __builtin_bit_cast(u32, a) + 0x8000u;
    u32 ub = __builtin_bit_cast(u32, b) + 0x8000u;
    return __builtin_amdgcn_perm(ub, ua, 0x07060302u);
}

__device__ __forceinline__ bf16x8 cvt8(float4 a, float4 b) {
    union { u32 u[4]; bf16x8 v; } r;
    r.u[0] = packbf(a.x, a.y); r.u[1] = packbf(a.z, a.w);
    r.u[2] = packbf(b.x, b.y); r.u[3] = packbf(b.z, b.w);
    return r.v;
}

__device__ __forceinline__ __bf16 f2bf(float f) {
    u32 u = __builtin_bit_cast(u32, f) + 0x8000u;
    unsigned short s = (unsigned short)(u >> 16);
    return __builtin_bit_cast(__bf16, s);
}

// HW DMA global->LDS, 16B per lane. LDS dest must be the WAVE-UNIFORM lane-0
// base; HW adds lane*16B. Global source is per-lane.
__device__ __forceinline__ void gl16(const __bf16* g, __bf16* l) {
    __builtin_amdgcn_global_load_lds(
        (const __attribute__((address_space(1))) unsigned int*)g,
        (__attribute__((address_space(3))) unsigned int*)l,
        16, 0, 0);
}

// ---------------------------------------------------------------------------
// Workspace layouts — ALL fragment-major, ALL R4/R7-hardware-verified:
//   Q: bh*131072 + qt*4096 + nt*1024 + j*512 + lane*8     (nt: 16-row group)
//   K: bh*131072 + sigma*2048 + mt*1024 + j*512 + lane*8  (sigma: 32-row slab)
//   V: bh*131072 + sigma*2048 + dt*512           + lane*8 (same 32-col slabs)
// Attn reads 32-row slabs sigma = kt*2 + wk. No proj change.
// ---------------------------------------------------------------------------

// ---------------------------------------------------------------------------
// Kernel 1: QKV projections — R4/R6/R7/R8 VERBATIM (hardware-verified).
// NOTE (R8 post-mortem): proj has never appeared in the top-5 profile; by
// elimination it costs ~70-75us (total - attn - overhead) vs a ~10-15us
// roofline. DO NOT TOUCH this round — the attn change below is sized to
// pull proj into the top-5 so the next round can attack it with counters.
// ---------------------------------------------------------------------------
__global__ __launch_bounds__(256, 4) void proj_kernel(
    const float* __restrict__ x,
    const float* __restrict__ wq, const float* __restrict__ bq,
    const float* __restrict__ wk, const float* __restrict__ bk,
    const float* __restrict__ wv, const float* __restrict__ bv,
    __bf16* __restrict__ qws, __bf16* __restrict__ kws, __bf16* __restrict__ vtws)
{
    const int st = blockIdx.x, h = blockIdx.y, b = blockIdx.z;
    const int s0 = st * 64;
    const int tid = threadIdx.x;

    __shared__ __align__(16) __bf16 Xs[64 * XPITCH];
    __shared__ __align__(16) __bf16 Tv[64 * XPITCH];

    const int r = tid >> 2, f = tid & 3;
    const int lane = tid & 63, w = tid >> 6, col = lane & 15, quad = lane >> 4;

    const size_t wrow = (size_t)(h * NDH + w * 16 + col) * NDH;
    const float* wq0 = wq + wrow + quad * 8;
    const float* wk0 = wk + wrow + quad * 8;
    const float* wv0 = wv + wrow + quad * 8;
    const bf16x8 wqa0 = cvt8(*(const float4*)(wq0),      *(const float4*)(wq0 + 4));
    const bf16x8 wqa1 = cvt8(*(const float4*)(wq0 + 32), *(const float4*)(wq0 + 36));
    const bf16x8 wka0 = cvt8(*(const float4*)(wk0),      *(const float4*)(wk0 + 4));
    const bf16x8 wka1 = cvt8(*(const float4*)(wk0 + 32), *(const float4*)(wk0 + 36));
    const bf16x8 wva0 = cvt8(*(const float4*)(wv0),      *(const float4*)(wv0 + 4));
    const bf16x8 wva1 = cvt8(*(const float4*)(wv0 + 32), *(const float4*)(wv0 + 36));

    float bqs[4], bks[4], bvs[4];
#pragma unroll
    for (int rr = 0; rr < 4; ++rr) {
        const int e = h * NDH + w * 16 + quad * 4 + rr;
        bqs[rr] = bq[e] * SSCALE;
        bks[rr] = bk[e];
        bvs[rr] = bv[e];
    }

    const size_t bh = (size_t)(b * NH + h);

    {
        const float* xrow = x + (size_t)(b * NS + s0 + r) * ND + h * NDH + f * 16;
        const float4 v0 = *(const float4*)(xrow);
        const float4 v1 = *(const float4*)(xrow + 4);
        const float4 v2 = *(const float4*)(xrow + 8);
        const float4 v3 = *(const float4*)(xrow + 12);
        *(bf16x8*)&Xs[r * XPITCH + f * 16]     = cvt8(v0, v1);
        *(bf16x8*)&Xs[r * XPITCH + f * 16 + 8] = cvt8(v2, v3);
    }
    __syncthreads();

    // lane-constant pieces of the fragment-layout address (e-side):
    // e0 = w*16 + quad*4 = 32*jj + 8*qa + 4*hf
    const int e0 = w * 16 + quad * 4;
    const int jj = e0 >> 5;            // j (0/1)
    const int qa = (e0 >> 3) & 3;      // quad_attn
    const int hf = (e0 >> 2) & 1;      // which uint2 half of the 16B chunk
    const int Lf = qa * 16 + col;      // fragment lane
    const int kt = st >> 1;            // 128-row K-tile index

#pragma unroll
    for (int nt = 0; nt < 4; ++nt) {
        const bf16x8 xb0 = *(const bf16x8*)&Xs[(nt * 16 + col) * XPITCH + quad * 8];
        const bf16x8 xb1 = *(const bf16x8*)&Xs[(nt * 16 + col) * XPITCH + 32 + quad * 8];
        f32x4 aq = {0.f, 0.f, 0.f, 0.f};
        f32x4 ak = {0.f, 0.f, 0.f, 0.f};
        f32x4 av = {0.f, 0.f, 0.f, 0.f};
        aq = MFMA16(wqa0, xb0, aq); aq = MFMA16(wqa1, xb1, aq);
        ak = MFMA16(wka0, xb0, ak); ak = MFMA16(wka1, xb1, ak);
        av = MFMA16(wva0, xb0, av); av = MFMA16(wva1, xb1, av);

        union { u32 u[2]; uint2 v; } pq, pk;
        pq.u[0] = packbf(fmaf(aq[0], SSCALE, bqs[0]), fmaf(aq[1], SSCALE, bqs[1]));
        pq.u[1] = packbf(fmaf(aq[2], SSCALE, bqs[2]), fmaf(aq[3], SSCALE, bqs[3]));
        pk.u[0] = packbf(ak[0] + bks[0], ak[1] + bks[1]);
        pk.u[1] = packbf(ak[2] + bks[2], ak[3] + bks[3]);

        // fragment-major stores (R4-verified)
        const int wa = (st & 1) * 2 + (nt >> 1);   // 32-row slab within 128-tile
        const int mt = nt & 1;
        const size_t kidx = ((((((size_t)bh * 16 + kt) * 4 + wa) * 2 + mt) * 2 + jj) * 64 + Lf) * 8 + hf * 4;
        const size_t qidx = (((((size_t)bh * 32 + st) * 4 + nt) * 2 + jj) * 64 + Lf) * 8 + hf * 4;
        *(uint2*)(kws + kidx) = pk.v;
        *(uint2*)(qws + qidx) = pq.v;

        const int pos = ((nt >> 1) << 5) + ((col >> 2) << 3) + ((nt & 1) << 2) + (col & 3);
#pragma unroll
        for (int rr = 0; rr < 4; ++rr)
            Tv[(w * 16 + quad * 4 + rr) * XPITCH + pos] = f2bf(av[rr] + bvs[rr]);
    }
    __syncthreads();

    {
        const uint4 v0 = *(const uint4*)&Tv[r * XPITCH + f * 16];
        const uint4 v1 = *(const uint4*)&Tv[r * XPITCH + f * 16 + 8];
        // thread (r,f) holds V^T[d=r][s0 + f*16 .. +15] = two 8-s chunks (R4-verified)
        const int wv_ = (st & 1) * 2 + (f >> 1);
        const int dtv = r >> 4;
        const int colv = r & 15;
        const int L0 = ((f & 1) * 2 + 0) * 16 + colv;
        const int L1 = ((f & 1) * 2 + 1) * 16 + colv;
        const size_t vbase = (((size_t)bh * 16 + kt) * 4 + wv_) * 4 + dtv;
        *(uint4*)(vtws + (vbase * 64 + L0) * 8) = v0;
        *(uint4*)(vtws + (vbase * 64 + L1) * 8) = v1;
    }
}

// ---------------------------------------------------------------------------
// Kernel 2: flash attention WITHOUT online max (scores statically bounded;
// exp2 direct). R8 counted-vmcnt pipeline kept VERBATIM in structure.
//
// NEW this round — 2 q-tiles per block (R8 post-mortem: grid 1536 = 6
// blocks/CU with 4 resident -> tail-limited occupancy 32%; VALU ~430 vs
// wall 937 cyc/wave-iter = 50% stall that TLP would absorb):
//   grid 768 = 3 blocks/CU EXACT, 768 <= 256x3 resident -> ALL blocks
//   co-resident, zero tail, zero ramp. The K-loop is shared: one ka/va
//   fetch serves both q-tiles (K/V traffic + DMA per unit work HALVED).
//   Registers: acc 2x32=64 AGPR + qb 32 + ka8 + va8 + pb8 + addr ~20
//   ~= 140 unified — R3's proven (256,3) register load (no spill at 168).
//   Iteration: [va issue; vmcnt(4) K-landed; ds_read ka; DMA K(kt+1);
//   QK(q2=0)+exp2; vmcnt(4) va-landed (K kt+1 in flight); PV(0);
//   QK(q2=1)+exp2; PV(1)]. Last iter: vmcnt(0).
// s_setprio OUT (R3). XCD-bijective decode: 768 = 8 XCD x 6 groups x 16 qtp.
// LDS: K dbuf [0,32768) | lbuf [32768,33280); epilogue slab aliases
// [0,17408), run twice (once per q-tile) with barrier separation.
// ---------------------------------------------------------------------------
__global__ __launch_bounds__(256, 3) void attn_kernel(
    const __bf16* __restrict__ qws, const __bf16* __restrict__ kws,
    const __bf16* __restrict__ vtws, float* __restrict__ out)
{
    // XCD-aware bijective decode: 768 blocks = 8 xcd x (6 groups x 16 qtp)
    const int bid = blockIdx.x;
    const int xcd = bid & 7;
    const int j   = bid >> 3;            // 0..95
    const int g   = xcd * 6 + (j >> 4);  // (b,h) group 0..47
    const int qtp = j & 15;              // q-tile PAIR index (2 tiles each)
    const int h   = g % NH;
    const int b   = g / NH;

    const int tid = threadIdx.x;

    __shared__ __align__(16) unsigned char smem[33280];
    __bf16* ldsK = (__bf16*)smem;                // 2 bufs x 4 waves x 4KB = 32 KB
    float* slab  = (float*)smem;                 // 64 x 68 f32 (epilogue, aliases)
    float* lbuf  = (float*)(smem + 32768);       // 128 f32 (no alias)

    const size_t bh = (size_t)(b * NH + h);
    const int lane = tid & 63, w = tid >> 6, col = lane & 15, quad = lane >> 4;
    const int wq = w >> 1, wk = w & 1;

    // Q fragments for BOTH q-tiles: rows (qtp*2+q2)*64 + wq*32 + nt*16 + col
    bf16x8 qb0[2][2], qb1[2][2];
    {
        const __bf16* qp = qws + (size_t)bh * 131072 + (size_t)qtp * 8192
                         + wq * 2048 + lane * 8;
#pragma unroll
        for (int q2 = 0; q2 < 2; ++q2)
#pragma unroll
            for (int nt = 0; nt < 2; ++nt) {
                qb0[q2][nt] = *(const bf16x8*)(qp + q2 * 4096 + nt * 1024);
                qb1[q2][nt] = *(const bf16x8*)(qp + q2 * 4096 + nt * 1024 + 512);
            }
    }

    // fragment-major global bases: slab sigma = kt*2 + wk (32 rows each)
    const __bf16* kg = kws  + (size_t)bh * 131072 + wk * 2048 + lane * 8;  // per-lane src
    const __bf16* vg = vtws + (size_t)bh * 131072 + wk * 2048 + lane * 8;
    __bf16* lk0 = ldsK + w * 2048;               // wave-uniform DMA dest, buf0
    __bf16* lk1 = ldsK + 8192 + w * 2048;        // buf1
    const __bf16* lkr0 = lk0 + lane * 8;         // per-lane read base
    const __bf16* lkr1 = lk1 + lane * 8;

    float l[2][2] = {{0.f, 0.f}, {0.f, 0.f}};
    f32x4 o[2][4][2];
#pragma unroll
    for (int q2 = 0; q2 < 2; ++q2)
#pragma unroll
        for (int dt = 0; dt < 4; ++dt)
#pragma unroll
            for (int nt = 0; nt < 2; ++nt) o[q2][dt][nt] = (f32x4){0.f, 0.f, 0.f, 0.f};

    // QK + softmax + PV for one q-tile. DO_WAIT: place the counted va-wait
    // before this q-tile's PV (first q-tile only).
#define QKPV(q2, DO_WAIT, PV_LAST) do {                                       \
        union { u32 u[4]; bf16x8 v; } pb[2];                                  \
        _Pragma("unroll")                                                     \
        for (int nt = 0; nt < 2; ++nt) {                                      \
            f32x4 sA = {0.f, 0.f, 0.f, 0.f};                                  \
            f32x4 sB = {0.f, 0.f, 0.f, 0.f};                                  \
            sA = MFMA16(ka00, qb0[q2][nt], sA);                               \
            sA = MFMA16(ka01, qb1[q2][nt], sA);                               \
            sB = MFMA16(ka10, qb0[q2][nt], sB);                               \
            sB = MFMA16(ka11, qb1[q2][nt], sB);                               \
            const float p0 = __builtin_amdgcn_exp2f(sA[0]);                   \
            const float p1 = __builtin_amdgcn_exp2f(sA[1]);                   \
            const float p2 = __builtin_amdgcn_exp2f(sA[2]);                   \
            const float p3 = __builtin_amdgcn_exp2f(sA[3]);                   \
            const float p4 = __builtin_amdgcn_exp2f(sB[0]);                   \
            const float p5 = __builtin_amdgcn_exp2f(sB[1]);                   \
            const float p6 = __builtin_amdgcn_exp2f(sB[2]);                   \
            const float p7 = __builtin_amdgcn_exp2f(sB[3]);                   \
            l[q2][nt] += ((p0 + p1) + (p2 + p3)) + ((p4 + p5) + (p6 + p7));   \
            pb[nt].u[0] = packbf(p0, p1);                                     \
            pb[nt].u[1] = packbf(p2, p3);                                     \
            pb[nt].u[2] = packbf(p4, p5);                                     \
            pb[nt].u[3] = packbf(p6, p7);                                     \
        }                                                                     \
        if (DO_WAIT) {                                                        \
            __builtin_amdgcn_sched_barrier(0);                                \
            if (PV_LAST) { asm volatile("s_waitcnt vmcnt(0)" ::: "memory"); } \
            else         { asm volatile("s_waitcnt vmcnt(4)" ::: "memory"); } \
            __builtin_amdgcn_sched_barrier(0);                                \
        }                                                                     \
        _Pragma("unroll")                                                     \
        for (int nt = 0; nt < 2; ++nt) {                                      \
            o[q2][0][nt] = MFMA16(va0, pb[nt].v, o[q2][0][nt]);               \
            o[q2][1][nt] = MFMA16(va1, pb[nt].v, o[q2][1][nt]);               \
            o[q2][2][nt] = MFMA16(va2, pb[nt].v, o[q2][2][nt]);               \
            o[q2][3][nt] = MFMA16(va3, pb[nt].v, o[q2][3][nt]);               \
        }                                                                     \
    } while (0)

    // one iteration: kt, read buf LKRD, DMA(kt+1)->LKN if DMA_C
#define ATTN_ITER(ktv, LKRD, LKN, DMA_C, PV_LAST) do {                        \
        const __bf16* _vp = vg + (size_t)(ktv) * 4096;                        \
        const bf16x8 va0 = *(const bf16x8*)(_vp);                             \
        const bf16x8 va1 = *(const bf16x8*)(_vp + 512);                       \
        const bf16x8 va2 = *(const bf16x8*)(_vp + 1024);                      \
        const bf16x8 va3 = *(const bf16x8*)(_vp + 1536);                      \
        __builtin_amdgcn_sched_barrier(0);                                    \
        asm volatile("s_waitcnt vmcnt(4)" ::: "memory");                      \
        __builtin_amdgcn_sched_barrier(0);                                    \
        const bf16x8 ka00 = *(const bf16x8*)(LKRD);                           \
        const bf16x8 ka01 = *(const bf16x8*)(LKRD + 512);                     \
        const bf16x8 ka10 = *(const bf16x8*)(LKRD + 1024);                    \
        const bf16x8 ka11 = *(const bf16x8*)(LKRD + 1536);                    \
        if (DMA_C) {                                                          \
            const __bf16* _kn = kg + (size_t)((ktv) + 1) * 4096;              \
            gl16(_kn,        LKN);        gl16(_kn + 512,  LKN + 512);        \
            gl16(_kn + 1024, LKN + 1024); gl16(_kn + 1536, LKN + 1536);       \
        }                                                                     \
        { QKPV(0, true, PV_LAST); }                                           \
        { QKPV(1, false, false); }                                            \
    } while (0)

    // ---- prologue: DMA K tile 0 -> buf0 (queue = [K0 x4]) ----
    gl16(kg,        lk0);        gl16(kg + 512,  lk0 + 512);
    gl16(kg + 1024, lk0 + 1024); gl16(kg + 1536, lk0 + 1536);

    for (int kt2 = 0; kt2 < 30; kt2 += 2) {
        ATTN_ITER(kt2,     lkr0, lk1, true, false);   // read buf0, DMA->buf1
        ATTN_ITER(kt2 + 1, lkr1, lk0, true, false);   // read buf1, DMA->buf0
    }
    ATTN_ITER(30, lkr0, lk1, true,  false);           // DMA(31)->buf1
    ATTN_ITER(31, lkr1, lk0, false, true);            // no DMA; final vmcnt(0)
#undef ATTN_ITER
#undef QKPV

    // cross-quad l reduction: per q-tile, per q=nt*16+col
#pragma unroll
    for (int q2 = 0; q2 < 2; ++q2)
#pragma unroll
        for (int nt = 0; nt < 2; ++nt) {
            l[q2][nt] += __shfl_xor(l[q2][nt], 16, 64);
            l[q2][nt] += __shfl_xor(l[q2][nt], 32, 64);
        }

    __syncthreads();   // all waves done with K slabs; epilogue regions free

#pragma unroll
    for (int q2 = 0; q2 < 2; ++q2) {
        const int q0 = (qtp * 2 + q2) * 64;

        if (quad == 0) {
#pragma unroll
            for (int nt = 0; nt < 2; ++nt)
                lbuf[wk * 64 + wq * 32 + nt * 16 + col] = l[q2][nt];
        }
        __syncthreads();

        float scale[2];
#pragma unroll
        for (int nt = 0; nt < 2; ++nt) {
            const int ri = wq * 32 + nt * 16 + col;
            scale[nt] = 1.0f / (lbuf[ri] + lbuf[64 + ri]);
        }
#pragma unroll
        for (int dt = 0; dt < 4; ++dt)
#pragma unroll
            for (int nt = 0; nt < 2; ++nt) o[q2][dt][nt] *= scale[nt];

        if (wk == 0) {
#pragma unroll
            for (int dt = 0; dt < 4; ++dt)
#pragma unroll
                for (int nt = 0; nt < 2; ++nt)
                    *(f32x4*)&slab[(wq * 32 + nt * 16 + col) * 68 + dt * 16 + quad * 4] = o[q2][dt][nt];
        }
        __syncthreads();
        if (wk == 1) {
#pragma unroll
            for (int dt = 0; dt < 4; ++dt)
#pragma unroll
                for (int nt = 0; nt < 2; ++nt) {
                    f32x4* p = (f32x4*)&slab[(wq * 32 + nt * 16 + col) * 68 + dt * 16 + quad * 4];
                    *p = *p + o[q2][dt][nt];
                }
        }
        __syncthreads();

        const int qr = tid >> 2, fq = tid & 3;
#pragma unroll
        for (int j2 = 0; j2 < 4; ++j2) {
            const f32x4 a = *(const f32x4*)&slab[qr * 68 + fq * 16 + j2 * 4];
            *(f32x4*)&out[(size_t)(b * NS + q0 + qr) * ND + h * NDH + fq * 16 + j2 * 4] = a;
        }
        __syncthreads();   // slab+lbuf reused by next q-tile
    }
}

extern "C" void kernel_launch(void* const* d_in, const int* in_sizes, int n_in,
                              void* d_out, int out_size, void* d_ws, size_t ws_size,
                              hipStream_t stream) {
    (void)in_sizes; (void)n_in; (void)out_size; (void)ws_size;
    const float* x  = (const float*)d_in[0];
    const float* wq = (const float*)d_in[1];
    const float* bq = (const float*)d_in[2];
    const float* wk = (const float*)d_in[3];
    const float* bk = (const float*)d_in[4];
    const float* wv = (const float*)d_in[5];
    const float* bv = (const float*)d_in[6];
    float* out = (float*)d_out;

    __bf16* qws  = (__bf16*)d_ws;
    __bf16* kws  = qws + (size_t)NB * NH * NS * NDH;
    __bf16* vtws = kws + (size_t)NB * NH * NS * NDH;

    dim3 grid(NS / 64, NH, NB);
    proj_kernel<<<grid, 256, 0, stream>>>(x, wq, bq, wk, bk, wv, bv, qws, kws, vtws);
    attn_kernel<<<dim3(768), 256, 0, stream>>>(qws, kws, vtws, out);
}

// Round 11
// 163.293 us; speedup vs baseline: 1.8378x; 1.8378x over previous
//
#include <hip/hip_runtime.h>

#define NB 4
#define NS 2048
#define ND 768
#define NH 12
#define NDH 64
#define XPITCH 72
#define SSCALE 0.18033688011112043f   // (1/sqrt(64)) * log2(e)

typedef __bf16 bf16x8 __attribute__((ext_vector_type(8)));
typedef float  f32x4  __attribute__((ext_vector_type(4)));
typedef unsigned int u32;

#define MFMA16(a, b, c) __builtin_amdgcn_mfma_f32_16x16x32_bf16(a, b, c, 0, 0, 0)

__device__ __forceinline__ u32 packbf(float a, float b) {
    u32 ua = __builtin_bit_cast(u32, a) + 0x8000u;
    u32 ub = __builtin_bit_cast(u32, b) + 0x8000u;
    return __builtin_amdgcn_perm(ub, ua, 0x07060302u);
}

__device__ __forceinline__ bf16x8 cvt8(float4 a, float4 b) {
    union { u32 u[4]; bf16x8 v; } r;
    r.u[0] = packbf(a.x, a.y); r.u[1] = packbf(a.z, a.w);
    r.u[2] = packbf(b.x, b.y); r.u[3] = packbf(b.z, b.w);
    return r.v;
}

__device__ __forceinline__ __bf16 f2bf(float f) {
    u32 u = __builtin_bit_cast(u32, f) + 0x8000u;
    unsigned short s = (unsigned short)(u >> 16);
    return __builtin_bit_cast(__bf16, s);
}

// HW DMA global->LDS, 16B per lane. LDS dest must be the WAVE-UNIFORM lane-0
// base; HW adds lane*16B. Global source is per-lane.
__device__ __forceinline__ void gl16(const __bf16* g, __bf16* l) {
    __builtin_amdgcn_global_load_lds(
        (const __attribute__((address_space(1))) unsigned int*)g,
        (__attribute__((address_space(3))) unsigned int*)l,
        16, 0, 0);
}

// ---------------------------------------------------------------------------
// Workspace layouts — ALL fragment-major, ALL R4/R7-hardware-verified:
//   Q: bh*131072 + qt*4096 + nt*1024 + j*512 + lane*8     (nt: 16-row group)
//   K: bh*131072 + sigma*2048 + mt*1024 + j*512 + lane*8  (sigma: 32-row slab)
//   V: bh*131072 + sigma*2048 + dt*512           + lane*8 (same 32-col slabs)
// Attn reads 32-row slabs sigma = kt*2 + wk. No proj change.
// ---------------------------------------------------------------------------

// ---------------------------------------------------------------------------
// Kernel 1: QKV projections — R4/R6/R7/R8 VERBATIM (hardware-verified).
// ---------------------------------------------------------------------------
__global__ __launch_bounds__(256, 4) void proj_kernel(
    const float* __restrict__ x,
    const float* __restrict__ wq, const float* __restrict__ bq,
    const float* __restrict__ wk, const float* __restrict__ bk,
    const float* __restrict__ wv, const float* __restrict__ bv,
    __bf16* __restrict__ qws, __bf16* __restrict__ kws, __bf16* __restrict__ vtws)
{
    const int st = blockIdx.x, h = blockIdx.y, b = blockIdx.z;
    const int s0 = st * 64;
    const int tid = threadIdx.x;

    __shared__ __align__(16) __bf16 Xs[64 * XPITCH];
    __shared__ __align__(16) __bf16 Tv[64 * XPITCH];

    const int r = tid >> 2, f = tid & 3;
    const int lane = tid & 63, w = tid >> 6, col = lane & 15, quad = lane >> 4;

    const size_t wrow = (size_t)(h * NDH + w * 16 + col) * NDH;
    const float* wq0 = wq + wrow + quad * 8;
    const float* wk0 = wk + wrow + quad * 8;
    const float* wv0 = wv + wrow + quad * 8;
    const bf16x8 wqa0 = cvt8(*(const float4*)(wq0),      *(const float4*)(wq0 + 4));
    const bf16x8 wqa1 = cvt8(*(const float4*)(wq0 + 32), *(const float4*)(wq0 + 36));
    const bf16x8 wka0 = cvt8(*(const float4*)(wk0),      *(const float4*)(wk0 + 4));
    const bf16x8 wka1 = cvt8(*(const float4*)(wk0 + 32), *(const float4*)(wk0 + 36));
    const bf16x8 wva0 = cvt8(*(const float4*)(wv0),      *(const float4*)(wv0 + 4));
    const bf16x8 wva1 = cvt8(*(const float4*)(wv0 + 32), *(const float4*)(wv0 + 36));

    float bqs[4], bks[4], bvs[4];
#pragma unroll
    for (int rr = 0; rr < 4; ++rr) {
        const int e = h * NDH + w * 16 + quad * 4 + rr;
        bqs[rr] = bq[e] * SSCALE;
        bks[rr] = bk[e];
        bvs[rr] = bv[e];
    }

    const size_t bh = (size_t)(b * NH + h);

    {
        const float* xrow = x + (size_t)(b * NS + s0 + r) * ND + h * NDH + f * 16;
        const float4 v0 = *(const float4*)(xrow);
        const float4 v1 = *(const float4*)(xrow + 4);
        const float4 v2 = *(const float4*)(xrow + 8);
        const float4 v3 = *(const float4*)(xrow + 12);
        *(bf16x8*)&Xs[r * XPITCH + f * 16]     = cvt8(v0, v1);
        *(bf16x8*)&Xs[r * XPITCH + f * 16 + 8] = cvt8(v2, v3);
    }
    __syncthreads();

    // lane-constant pieces of the fragment-layout address (e-side):
    // e0 = w*16 + quad*4 = 32*jj + 8*qa + 4*hf
    const int e0 = w * 16 + quad * 4;
    const int jj = e0 >> 5;            // j (0/1)
    const int qa = (e0 >> 3) & 3;      // quad_attn
    const int hf = (e0 >> 2) & 1;      // which uint2 half of the 16B chunk
    const int Lf = qa * 16 + col;      // fragment lane
    const int kt = st >> 1;            // 128-row K-tile index

#pragma unroll
    for (int nt = 0; nt < 4; ++nt) {
        const bf16x8 xb0 = *(const bf16x8*)&Xs[(nt * 16 + col) * XPITCH + quad * 8];
        const bf16x8 xb1 = *(const bf16x8*)&Xs[(nt * 16 + col) * XPITCH + 32 + quad * 8];
        f32x4 aq = {0.f, 0.f, 0.f, 0.f};
        f32x4 ak = {0.f, 0.f, 0.f, 0.f};
        f32x4 av = {0.f, 0.f, 0.f, 0.f};
        aq = MFMA16(wqa0, xb0, aq); aq = MFMA16(wqa1, xb1, aq);
        ak = MFMA16(wka0, xb0, ak); ak = MFMA16(wka1, xb1, ak);
        av = MFMA16(wva0, xb0, av); av = MFMA16(wva1, xb1, av);

        union { u32 u[2]; uint2 v; } pq, pk;
        pq.u[0] = packbf(fmaf(aq[0], SSCALE, bqs[0]), fmaf(aq[1], SSCALE, bqs[1]));
        pq.u[1] = packbf(fmaf(aq[2], SSCALE, bqs[2]), fmaf(aq[3], SSCALE, bqs[3]));
        pk.u[0] = packbf(ak[0] + bks[0], ak[1] + bks[1]);
        pk.u[1] = packbf(ak[2] + bks[2], ak[3] + bks[3]);

        // fragment-major stores (R4-verified)
        const int wa = (st & 1) * 2 + (nt >> 1);   // 32-row slab within 128-tile
        const int mt = nt & 1;
        const size_t kidx = ((((((size_t)bh * 16 + kt) * 4 + wa) * 2 + mt) * 2 + jj) * 64 + Lf) * 8 + hf * 4;
        const size_t qidx = (((((size_t)bh * 32 + st) * 4 + nt) * 2 + jj) * 64 + Lf) * 8 + hf * 4;
        *(uint2*)(kws + kidx) = pk.v;
        *(uint2*)(qws + qidx) = pq.v;

        const int pos = ((nt >> 1) << 5) + ((col >> 2) << 3) + ((nt & 1) << 2) + (col & 3);
#pragma unroll
        for (int rr = 0; rr < 4; ++rr)
            Tv[(w * 16 + quad * 4 + rr) * XPITCH + pos] = f2bf(av[rr] + bvs[rr]);
    }
    __syncthreads();

    {
        const uint4 v0 = *(const uint4*)&Tv[r * XPITCH + f * 16];
        const uint4 v1 = *(const uint4*)&Tv[r * XPITCH + f * 16 + 8];
        // thread (r,f) holds V^T[d=r][s0 + f*16 .. +15] = two 8-s chunks (R4-verified)
        const int wv_ = (st & 1) * 2 + (f >> 1);
        const int dtv = r >> 4;
        const int colv = r & 15;
        const int L0 = ((f & 1) * 2 + 0) * 16 + colv;
        const int L1 = ((f & 1) * 2 + 1) * 16 + colv;
        const size_t vbase = (((size_t)bh * 16 + kt) * 4 + wv_) * 4 + dtv;
        *(uint4*)(vtws + (vbase * 64 + L0) * 8) = v0;
        *(uint4*)(vtws + (vbase * 64 + L1) * 8) = v1;
    }
}

// ---------------------------------------------------------------------------
// Kernel 2: flash attention WITHOUT online max (scores statically bounded;
// exp2 direct). Loop is BYTE-IDENTICAL to R8 (verified 75.3us, no spill:
// arch 64 + acc 32 = 96 unified).
//
// R11 single edit (R10 lesson: one change per round; R10 bundled cvtpk
// inline-asm — prime NaN suspect: codegen perturbation around hand-counted
// vmcnt(N), where any compiler-inserted VMEM op breaks the count — with the
// LDS shrink; cvtpk REVERTED, packbf restored):
//   LDS 33280 -> 32768 B: lbuf moved to bytes [17408,17920) inside K buf1.
//   Safe: every wave drains its DMA queue (vmcnt(0), PV_LAST) before the
//   first post-loop __syncthreads; lbuf is only touched after that barrier.
//   5 x 32768 = 163840 = full 160 KiB pool -> residency 4 -> 5 blocks/CU
//   (registers at ~96 unified allow 5+). launch_bounds (256,4) is a floor,
//   not a cap; worst case falls back to 4 resident, never spills.
// s_setprio OUT (R3). XCD-bijective decode kept (R3: FETCH 109->24MB).
// LDS: K dbuf [0,32768); lbuf [17408,17920) post-loop; epilogue slab
// aliases [0,17408). Total 32768 B.
// ---------------------------------------------------------------------------
__global__ __launch_bounds__(256, 4) void attn_kernel(
    const __bf16* __restrict__ qws, const __bf16* __restrict__ kws,
    const __bf16* __restrict__ vtws, float* __restrict__ out)
{
    // XCD-aware bijective decode: bid = xcd + 8*j, j = 32*(group within XCD) + qt
    const int bid = blockIdx.x;
    const int xcd = bid & 7;
    const int j   = bid >> 3;            // 0..191
    const int g   = xcd * 6 + (j >> 5);  // (b,h) group 0..47
    const int qt  = j & 31;
    const int h   = g % NH;
    const int b   = g / NH;

    const int q0 = qt * 64;
    const int tid = threadIdx.x;

    __shared__ __align__(16) unsigned char smem[32768];
    __bf16* ldsK = (__bf16*)smem;                // 2 bufs x 4 waves x 4KB = 32 KB
    float* slab  = (float*)smem;                 // 64 x 68 f32 (epilogue, aliases)
    float* lbuf  = (float*)(smem + 17408);       // 128 f32 (post-loop, aliases buf1)

    const size_t bh = (size_t)(b * NH + h);
    const int lane = tid & 63, w = tid >> 6, col = lane & 15, quad = lane >> 4;
    const int wq = w >> 1, wk = w & 1;

    // Q fragments: this wave's 32 q-rows (nt in {0,1} -> rows wq*32+nt*16+col)
    bf16x8 qb0[2], qb1[2];
    {
        const __bf16* qp = qws + (size_t)bh * 131072 + (size_t)qt * 4096
                         + wq * 2048 + lane * 8;
#pragma unroll
        for (int nt = 0; nt < 2; ++nt) {
            qb0[nt] = *(const bf16x8*)(qp + nt * 1024);
            qb1[nt] = *(const bf16x8*)(qp + nt * 1024 + 512);
        }
    }

    // fragment-major global bases: slab sigma = kt*2 + wk (32 rows each)
    const __bf16* kg = kws  + (size_t)bh * 131072 + wk * 2048 + lane * 8;  // per-lane src
    const __bf16* vg = vtws + (size_t)bh * 131072 + wk * 2048 + lane * 8;
    __bf16* lk0 = ldsK + w * 2048;               // wave-uniform DMA dest, buf0
    __bf16* lk1 = ldsK + 8192 + w * 2048;        // buf1
    const __bf16* lkr0 = lk0 + lane * 8;         // per-lane read base
    const __bf16* lkr1 = lk1 + lane * 8;

    float l[2] = {0.f, 0.f};
    f32x4 o[4][2];
#pragma unroll
    for (int dt = 0; dt < 4; ++dt)
#pragma unroll
        for (int nt = 0; nt < 2; ++nt) o[dt][nt] = (f32x4){0.f, 0.f, 0.f, 0.f};

    // one iteration: kt, read buf LKRD, DMA(kt+1)->LKN if DMA_C, PV-wait literal
#define ATTN_ITER(ktv, LKRD, LKN, DMA_C, PV_LAST) do {                        \
        const __bf16* _vp = vg + (size_t)(ktv) * 4096;                        \
        const bf16x8 va0 = *(const bf16x8*)(_vp);                             \
        const bf16x8 va1 = *(const bf16x8*)(_vp + 512);                       \
        const bf16x8 va2 = *(const bf16x8*)(_vp + 1024);                      \
        const bf16x8 va3 = *(const bf16x8*)(_vp + 1536);                      \
        __builtin_amdgcn_sched_barrier(0);                                    \
        asm volatile("s_waitcnt vmcnt(4)" ::: "memory");                      \
        __builtin_amdgcn_sched_barrier(0);                                    \
        const bf16x8 ka00 = *(const bf16x8*)(LKRD);                           \
        const bf16x8 ka01 = *(const bf16x8*)(LKRD + 512);                     \
        const bf16x8 ka10 = *(const bf16x8*)(LKRD + 1024);                    \
        const bf16x8 ka11 = *(const bf16x8*)(LKRD + 1536);                    \
        if (DMA_C) {                                                          \
            const __bf16* _kn = kg + (size_t)((ktv) + 1) * 4096;              \
            gl16(_kn,        LKN);        gl16(_kn + 512,  LKN + 512);        \
            gl16(_kn + 1024, LKN + 1024); gl16(_kn + 1536, LKN + 1536);       \
        }                                                                     \
        union { u32 u[4]; bf16x8 v; } pb[2];                                  \
        _Pragma("unroll")                                                     \
        for (int nt = 0; nt < 2; ++nt) {                                      \
            f32x4 sA = {0.f, 0.f, 0.f, 0.f};                                  \
            f32x4 sB = {0.f, 0.f, 0.f, 0.f};                                  \
            sA = MFMA16(ka00, qb0[nt], sA); sA = MFMA16(ka01, qb1[nt], sA);   \
            sB = MFMA16(ka10, qb0[nt], sB); sB = MFMA16(ka11, qb1[nt], sB);   \
            const float p0 = __builtin_amdgcn_exp2f(sA[0]);                   \
            const float p1 = __builtin_amdgcn_exp2f(sA[1]);                   \
            const float p2 = __builtin_amdgcn_exp2f(sA[2]);                   \
            const float p3 = __builtin_amdgcn_exp2f(sA[3]);                   \
            const float p4 = __builtin_amdgcn_exp2f(sB[0]);                   \
            const float p5 = __builtin_amdgcn_exp2f(sB[1]);                   \
            const float p6 = __builtin_amdgcn_exp2f(sB[2]);                   \
            const float p7 = __builtin_amdgcn_exp2f(sB[3]);                   \
            l[nt] += ((p0 + p1) + (p2 + p3)) + ((p4 + p5) + (p6 + p7));       \
            pb[nt].u[0] = packbf(p0, p1);                                     \
            pb[nt].u[1] = packbf(p2, p3);                                     \
            pb[nt].u[2] = packbf(p4, p5);                                     \
            pb[nt].u[3] = packbf(p6, p7);                                     \
        }                                                                     \
        __builtin_amdgcn_sched_barrier(0);                                    \
        if (PV_LAST) { asm volatile("s_waitcnt vmcnt(0)" ::: "memory"); }     \
        else         { asm volatile("s_waitcnt vmcnt(4)" ::: "memory"); }     \
        __builtin_amdgcn_sched_barrier(0);                                    \
        _Pragma("unroll")                                                     \
        for (int nt = 0; nt < 2; ++nt) {                                      \
            o[0][nt] = MFMA16(va0, pb[nt].v, o[0][nt]);                       \
            o[1][nt] = MFMA16(va1, pb[nt].v, o[1][nt]);                       \
            o[2][nt] = MFMA16(va2, pb[nt].v, o[2][nt]);                       \
            o[3][nt] = MFMA16(va3, pb[nt].v, o[3][nt]);                       \
        }                                                                     \
    } while (0)

    // ---- prologue: DMA K tile 0 -> buf0 (queue = [K0 x4]) ----
    gl16(kg,        lk0);        gl16(kg + 512,  lk0 + 512);
    gl16(kg + 1024, lk0 + 1024); gl16(kg + 1536, lk0 + 1536);

    for (int kt2 = 0; kt2 < 30; kt2 += 2) {
        ATTN_ITER(kt2,     lkr0, lk1, true, false);   // read buf0, DMA->buf1
        ATTN_ITER(kt2 + 1, lkr1, lk0, true, false);   // read buf1, DMA->buf0
    }
    ATTN_ITER(30, lkr0, lk1, true,  false);           // DMA(31)->buf1
    ATTN_ITER(31, lkr1, lk0, false, true);            // no DMA; final vmcnt(0)
#undef ATTN_ITER

    // cross-quad l reduction: sum over this wave's 32 k-rows per q=nt*16+col
#pragma unroll
    for (int nt = 0; nt < 2; ++nt) {
        l[nt] += __shfl_xor(l[nt], 16, 64);
        l[nt] += __shfl_xor(l[nt], 32, 64);
    }

    // ---- combine across the 2 wk waves per q-half ----
    __syncthreads();   // all waves drained their DMAs (vmcnt(0)) before here
    if (quad == 0) {
#pragma unroll
        for (int nt = 0; nt < 2; ++nt)
            lbuf[wk * 64 + wq * 32 + nt * 16 + col] = l[nt];
    }
    __syncthreads();

    float scale[2];
#pragma unroll
    for (int nt = 0; nt < 2; ++nt) {
        const int ri = wq * 32 + nt * 16 + col;
        scale[nt] = 1.0f / (lbuf[ri] + lbuf[64 + ri]);
    }
#pragma unroll
    for (int dt = 0; dt < 4; ++dt)
#pragma unroll
        for (int nt = 0; nt < 2; ++nt) o[dt][nt] *= scale[nt];

    // slab [0,17408) disjoint from lbuf [17408,17920); loop is done
    if (wk == 0) {
#pragma unroll
        for (int dt = 0; dt < 4; ++dt)
#pragma unroll
            for (int nt = 0; nt < 2; ++nt)
                *(f32x4*)&slab[(wq * 32 + nt * 16 + col) * 68 + dt * 16 + quad * 4] = o[dt][nt];
    }
    __syncthreads();
    if (wk == 1) {
#pragma unroll
        for (int dt = 0; dt < 4; ++dt)
#pragma unroll
            for (int nt = 0; nt < 2; ++nt) {
                f32x4* p = (f32x4*)&slab[(wq * 32 + nt * 16 + col) * 68 + dt * 16 + quad * 4];
                *p = *p + o[dt][nt];
            }
    }
    __syncthreads();

    const int qr = tid >> 2, fq = tid & 3;
#pragma unroll
    for (int j2 = 0; j2 < 4; ++j2) {
        const f32x4 a = *(const f32x4*)&slab[qr * 68 + fq * 16 + j2 * 4];
        *(f32x4*)&out[(size_t)(b * NS + q0 + qr) * ND + h * NDH + fq * 16 + j2 * 4] = a;
    }
}

extern "C" void kernel_launch(void* const* d_in, const int* in_sizes, int n_in,
                              void* d_out, int out_size, void* d_ws, size_t ws_size,
                              hipStream_t stream) {
    (void)in_sizes; (void)n_in; (void)out_size; (void)ws_size;
    const float* x  = (const float*)d_in[0];
    const float* wq = (const float*)d_in[1];
    const float* bq = (const float*)d_in[2];
    const float* wk = (const float*)d_in[3];
    const float* bk = (const float*)d_in[4];
    const float* wv = (const float*)d_in[5];
    const float* bv = (const float*)d_in[6];
    float* out = (float*)d_out;

    __bf16* qws  = (__bf16*)d_ws;
    __bf16* kws  = qws + (size_t)NB * NH * NS * NDH;
    __bf16* vtws = kws + (size_t)NB * NH * NS * NDH;

    dim3 grid(NS / 64, NH, NB);
    proj_kernel<<<grid, 256, 0, stream>>>(x, wq, bq, wk, bk, wv, bv, qws, kws, vtws);
    attn_kernel<<<dim3(NS / 64 * NH * NB), 256, 0, stream>>>(qws, kws, vtws, out);
}

// Round 12
// 160.120 us; speedup vs baseline: 1.8742x; 1.0198x over previous
//
#include <hip/hip_runtime.h>

#define NB 4
#define NS 2048
#define ND 768
#define NH 12
#define NDH 64
#define XPITCH 72
#define SSCALE 0.18033688011112043f   // (1/sqrt(64)) * log2(e)

typedef __bf16 bf16x8 __attribute__((ext_vector_type(8)));
typedef float  f32x4  __attribute__((ext_vector_type(4)));
typedef unsigned int u32;

#define MFMA16(a, b, c) __builtin_amdgcn_mfma_f32_16x16x32_bf16(a, b, c, 0, 0, 0)

__device__ __forceinline__ u32 packbf(float a, float b) {
    u32 ua = __builtin_bit_cast(u32, a) + 0x8000u;
    u32 ub = __builtin_bit_cast(u32, b) + 0x8000u;
    return __builtin_amdgcn_perm(ub, ua, 0x07060302u);
}

__device__ __forceinline__ bf16x8 cvt8(float4 a, float4 b) {
    union { u32 u[4]; bf16x8 v; } r;
    r.u[0] = packbf(a.x, a.y); r.u[1] = packbf(a.z, a.w);
    r.u[2] = packbf(b.x, b.y); r.u[3] = packbf(b.z, b.w);
    return r.v;
}

__device__ __forceinline__ __bf16 f2bf(float f) {
    u32 u = __builtin_bit_cast(u32, f) + 0x8000u;
    unsigned short s = (unsigned short)(u >> 16);
    return __builtin_bit_cast(__bf16, s);
}

// HW DMA global->LDS, 16B per lane. LDS dest must be the WAVE-UNIFORM lane-0
// base; HW adds lane*16B. Global source is per-lane.
__device__ __forceinline__ void gl16(const __bf16* g, __bf16* l) {
    __builtin_amdgcn_global_load_lds(
        (const __attribute__((address_space(1))) unsigned int*)g,
        (__attribute__((address_space(3))) unsigned int*)l,
        16, 0, 0);
}

// ---------------------------------------------------------------------------
// Workspace layouts — ALL fragment-major, ALL R4/R7-hardware-verified:
//   Q: bh*131072 + st*4096 + nt*1024 + j*512 + lane*8     (st: 64-row tile)
//   K: bh*131072 + sigma*2048 + mt*1024 + j*512 + lane*8  (sigma: 32-row slab)
//   V: bh*131072 + sigma*2048 + dt*512           + lane*8 (same 32-col slabs)
// Attn reads 32-row slabs sigma = kt*2 + wk.
// ---------------------------------------------------------------------------

// ---------------------------------------------------------------------------
// Kernel 1: QKV projections — REBUILT this round (decisive experiment on the
// unprofiled ~86us "rest"): 2 s-tiles (st = 2*stp, 2*stp+1) per block, grid
// (16,12,4)=768 = 3 blocks/CU exact (all co-resident, zero tail). Weights +
// biases converted ONCE per block (was per tile); X tile st1 prefetched into
// registers before the first barrier (HBM latency hides under tile-0
// compute); double-buffered Xs/Tv; 3 barriers per 2 tiles (was 4). Store
// addressing is the R4-verified fragment-major layout, generic in st.
// launch_bounds(256,3): budget 168 vs ~110 demand — no spill risk
// (R2/R4/R5/R9 rule). LDS 4 x 9216 = 36864 B (3 blocks = 110KB <= 160K).
// ---------------------------------------------------------------------------
__global__ __launch_bounds__(256, 3) void proj_kernel(
    const float* __restrict__ x,
    const float* __restrict__ wq, const float* __restrict__ bq,
    const float* __restrict__ wk, const float* __restrict__ bk,
    const float* __restrict__ wv, const float* __restrict__ bv,
    __bf16* __restrict__ qws, __bf16* __restrict__ kws, __bf16* __restrict__ vtws)
{
    const int stp = blockIdx.x, h = blockIdx.y, b = blockIdx.z;
    const int st0 = stp * 2, st1 = stp * 2 + 1;   // 64-row tile indices
    const int tid = threadIdx.x;

    __shared__ __align__(16) __bf16 Xs[2][64 * XPITCH];
    __shared__ __align__(16) __bf16 Tv[2][64 * XPITCH];

    const int r = tid >> 2, f = tid & 3;
    const int lane = tid & 63, w = tid >> 6, col = lane & 15, quad = lane >> 4;

    // ---- weights: loaded + converted ONCE per block (serves both tiles) ----
    const size_t wrow = (size_t)(h * NDH + w * 16 + col) * NDH;
    const float* wq0 = wq + wrow + quad * 8;
    const float* wk0 = wk + wrow + quad * 8;
    const float* wv0 = wv + wrow + quad * 8;
    const bf16x8 wqa0 = cvt8(*(const float4*)(wq0),      *(const float4*)(wq0 + 4));
    const bf16x8 wqa1 = cvt8(*(const float4*)(wq0 + 32), *(const float4*)(wq0 + 36));
    const bf16x8 wka0 = cvt8(*(const float4*)(wk0),      *(const float4*)(wk0 + 4));
    const bf16x8 wka1 = cvt8(*(const float4*)(wk0 + 32), *(const float4*)(wk0 + 36));
    const bf16x8 wva0 = cvt8(*(const float4*)(wv0),      *(const float4*)(wv0 + 4));
    const bf16x8 wva1 = cvt8(*(const float4*)(wv0 + 32), *(const float4*)(wv0 + 36));

    float bqs[4], bks[4], bvs[4];
#pragma unroll
    for (int rr = 0; rr < 4; ++rr) {
        const int e = h * NDH + w * 16 + quad * 4 + rr;
        bqs[rr] = bq[e] * SSCALE;
        bks[rr] = bk[e];
        bvs[rr] = bv[e];
    }

    const size_t bh = (size_t)(b * NH + h);

    // lane-constant pieces of the fragment-layout address (e-side)
    const int e0 = w * 16 + quad * 4;
    const int jj = e0 >> 5;            // j (0/1)
    const int qa = (e0 >> 3) & 3;      // quad_attn
    const int hf = (e0 >> 2) & 1;      // which uint2 half of the 16B chunk
    const int Lf = qa * 16 + col;      // fragment lane

    // ---- X tile 0 load -> Xs[0]; X tile 1 prefetch -> regs ----
    const float* xrow0 = x + (size_t)(b * NS + st0 * 64 + r) * ND + h * NDH + f * 16;
    const float* xrow1 = xrow0 + (size_t)64 * ND;
    {
        const float4 v0 = *(const float4*)(xrow0);
        const float4 v1 = *(const float4*)(xrow0 + 4);
        const float4 v2 = *(const float4*)(xrow0 + 8);
        const float4 v3 = *(const float4*)(xrow0 + 12);
        *(bf16x8*)&Xs[0][r * XPITCH + f * 16]     = cvt8(v0, v1);
        *(bf16x8*)&Xs[0][r * XPITCH + f * 16 + 8] = cvt8(v2, v3);
    }
    const float4 xn0 = *(const float4*)(xrow1);
    const float4 xn1 = *(const float4*)(xrow1 + 4);
    const float4 xn2 = *(const float4*)(xrow1 + 8);
    const float4 xn3 = *(const float4*)(xrow1 + 12);
    __syncthreads();

    auto do_tile = [&](int st, const __bf16* XsP, __bf16* TvP) {
        const int kt = st >> 1;
#pragma unroll
        for (int nt = 0; nt < 4; ++nt) {
            const bf16x8 xb0 = *(const bf16x8*)&XsP[(nt * 16 + col) * XPITCH + quad * 8];
            const bf16x8 xb1 = *(const bf16x8*)&XsP[(nt * 16 + col) * XPITCH + 32 + quad * 8];
            f32x4 aq = {0.f, 0.f, 0.f, 0.f};
            f32x4 ak = {0.f, 0.f, 0.f, 0.f};
            f32x4 av = {0.f, 0.f, 0.f, 0.f};
            aq = MFMA16(wqa0, xb0, aq); aq = MFMA16(wqa1, xb1, aq);
            ak = MFMA16(wka0, xb0, ak); ak = MFMA16(wka1, xb1, ak);
            av = MFMA16(wva0, xb0, av); av = MFMA16(wva1, xb1, av);

            union { u32 u[2]; uint2 v; } pq, pk;
            pq.u[0] = packbf(fmaf(aq[0], SSCALE, bqs[0]), fmaf(aq[1], SSCALE, bqs[1]));
            pq.u[1] = packbf(fmaf(aq[2], SSCALE, bqs[2]), fmaf(aq[3], SSCALE, bqs[3]));
            pk.u[0] = packbf(ak[0] + bks[0], ak[1] + bks[1]);
            pk.u[1] = packbf(ak[2] + bks[2], ak[3] + bks[3]);

            const int wa = (st & 1) * 2 + (nt >> 1);
            const int mt = nt & 1;
            const size_t kidx = ((((((size_t)bh * 16 + kt) * 4 + wa) * 2 + mt) * 2 + jj) * 64 + Lf) * 8 + hf * 4;
            const size_t qidx = (((((size_t)bh * 32 + st) * 4 + nt) * 2 + jj) * 64 + Lf) * 8 + hf * 4;
            *(uint2*)(kws + kidx) = pk.v;
            *(uint2*)(qws + qidx) = pq.v;

            const int pos = ((nt >> 1) << 5) + ((col >> 2) << 3) + ((nt & 1) << 2) + (col & 3);
#pragma unroll
            for (int rr = 0; rr < 4; ++rr)
                TvP[(w * 16 + quad * 4 + rr) * XPITCH + pos] = f2bf(av[rr] + bvs[rr]);
        }
    };

    auto v_store = [&](int st, const __bf16* TvP) {
        const uint4 v0 = *(const uint4*)&TvP[r * XPITCH + f * 16];
        const uint4 v1 = *(const uint4*)&TvP[r * XPITCH + f * 16 + 8];
        const int kt = st >> 1;
        const int wv_ = (st & 1) * 2 + (f >> 1);
        const int dtv = r >> 4;
        const int colv = r & 15;
        const int L0 = ((f & 1) * 2 + 0) * 16 + colv;
        const int L1 = ((f & 1) * 2 + 1) * 16 + colv;
        const size_t vbase = (((size_t)bh * 16 + kt) * 4 + wv_) * 4 + dtv;
        *(uint4*)(vtws + (vbase * 64 + L0) * 8) = v0;
        *(uint4*)(vtws + (vbase * 64 + L1) * 8) = v1;
    };

    // tile 0 compute + stage Xs[1] from prefetched regs
    do_tile(st0, Xs[0], Tv[0]);
    *(bf16x8*)&Xs[1][r * XPITCH + f * 16]     = cvt8(xn0, xn1);
    *(bf16x8*)&Xs[1][r * XPITCH + f * 16 + 8] = cvt8(xn2, xn3);
    __syncthreads();   // Tv[0] + Xs[1] visible

    v_store(st0, Tv[0]);
    do_tile(st1, Xs[1], Tv[1]);
    __syncthreads();   // Tv[1] visible
    v_store(st1, Tv[1]);
}

// ---------------------------------------------------------------------------
// Kernel 2: flash attention — R11 VERBATIM (verified 76.6us, no spill:
// arch 64 + acc 32 = 96 unified). LDS: K dbuf [0,32768); lbuf
// [17408,17920) post-loop; epilogue slab aliases [0,17408).
// ---------------------------------------------------------------------------
__global__ __launch_bounds__(256, 4) void attn_kernel(
    const __bf16* __restrict__ qws, const __bf16* __restrict__ kws,
    const __bf16* __restrict__ vtws, float* __restrict__ out)
{
    const int bid = blockIdx.x;
    const int xcd = bid & 7;
    const int j   = bid >> 3;            // 0..191
    const int g   = xcd * 6 + (j >> 5);  // (b,h) group 0..47
    const int qt  = j & 31;
    const int h   = g % NH;
    const int b   = g / NH;

    const int q0 = qt * 64;
    const int tid = threadIdx.x;

    __shared__ __align__(16) unsigned char smem[32768];
    __bf16* ldsK = (__bf16*)smem;
    float* slab  = (float*)smem;
    float* lbuf  = (float*)(smem + 17408);

    const size_t bh = (size_t)(b * NH + h);
    const int lane = tid & 63, w = tid >> 6, col = lane & 15, quad = lane >> 4;
    const int wq = w >> 1, wk = w & 1;

    bf16x8 qb0[2], qb1[2];
    {
        const __bf16* qp = qws + (size_t)bh * 131072 + (size_t)qt * 4096
                         + wq * 2048 + lane * 8;
#pragma unroll
        for (int nt = 0; nt < 2; ++nt) {
            qb0[nt] = *(const bf16x8*)(qp + nt * 1024);
            qb1[nt] = *(const bf16x8*)(qp + nt * 1024 + 512);
        }
    }

    const __bf16* kg = kws  + (size_t)bh * 131072 + wk * 2048 + lane * 8;
    const __bf16* vg = vtws + (size_t)bh * 131072 + wk * 2048 + lane * 8;
    __bf16* lk0 = ldsK + w * 2048;
    __bf16* lk1 = ldsK + 8192 + w * 2048;
    const __bf16* lkr0 = lk0 + lane * 8;
    const __bf16* lkr1 = lk1 + lane * 8;

    float l[2] = {0.f, 0.f};
    f32x4 o[4][2];
#pragma unroll
    for (int dt = 0; dt < 4; ++dt)
#pragma unroll
        for (int nt = 0; nt < 2; ++nt) o[dt][nt] = (f32x4){0.f, 0.f, 0.f, 0.f};

#define ATTN_ITER(ktv, LKRD, LKN, DMA_C, PV_LAST) do {                        \
        const __bf16* _vp = vg + (size_t)(ktv) * 4096;                        \
        const bf16x8 va0 = *(const bf16x8*)(_vp);                             \
        const bf16x8 va1 = *(const bf16x8*)(_vp + 512);                       \
        const bf16x8 va2 = *(const bf16x8*)(_vp + 1024);                      \
        const bf16x8 va3 = *(const bf16x8*)(_vp + 1536);                      \
        __builtin_amdgcn_sched_barrier(0);                                    \
        asm volatile("s_waitcnt vmcnt(4)" ::: "memory");                      \
        __builtin_amdgcn_sched_barrier(0);                                    \
        const bf16x8 ka00 = *(const bf16x8*)(LKRD);                           \
        const bf16x8 ka01 = *(const bf16x8*)(LKRD + 512);                     \
        const bf16x8 ka10 = *(const bf16x8*)(LKRD + 1024);                    \
        const bf16x8 ka11 = *(const bf16x8*)(LKRD + 1536);                    \
        if (DMA_C) {                                                          \
            const __bf16* _kn = kg + (size_t)((ktv) + 1) * 4096;              \
            gl16(_kn,        LKN);        gl16(_kn + 512,  LKN + 512);        \
            gl16(_kn + 1024, LKN + 1024); gl16(_kn + 1536, LKN + 1536);       \
        }                                                                     \
        union { u32 u[4]; bf16x8 v; } pb[2];                                  \
        _Pragma("unroll")                                                     \
        for (int nt = 0; nt < 2; ++nt) {                                      \
            f32x4 sA = {0.f, 0.f, 0.f, 0.f};                                  \
            f32x4 sB = {0.f, 0.f, 0.f, 0.f};                                  \
            sA = MFMA16(ka00, qb0[nt], sA); sA = MFMA16(ka01, qb1[nt], sA);   \
            sB = MFMA16(ka10, qb0[nt], sB); sB = MFMA16(ka11, qb1[nt], sB);   \
            const float p0 = __builtin_amdgcn_exp2f(sA[0]);                   \
            const float p1 = __builtin_amdgcn_exp2f(sA[1]);                   \
            const float p2 = __builtin_amdgcn_exp2f(sA[2]);                   \
            const float p3 = __builtin_amdgcn_exp2f(sA[3]);                   \
            const float p4 = __builtin_amdgcn_exp2f(sB[0]);                   \
            const float p5 = __builtin_amdgcn_exp2f(sB[1]);                   \
            const float p6 = __builtin_amdgcn_exp2f(sB[2]);                   \
            const float p7 = __builtin_amdgcn_exp2f(sB[3]);                   \
            l[nt] += ((p0 + p1) + (p2 + p3)) + ((p4 + p5) + (p6 + p7));       \
            pb[nt].u[0] = packbf(p0, p1);                                     \
            pb[nt].u[1] = packbf(p2, p3);                                     \
            pb[nt].u[2] = packbf(p4, p5);                                     \
            pb[nt].u[3] = packbf(p6, p7);                                     \
        }                                                                     \
        __builtin_amdgcn_sched_barrier(0);                                    \
        if (PV_LAST) { asm volatile("s_waitcnt vmcnt(0)" ::: "memory"); }     \
        else         { asm volatile("s_waitcnt vmcnt(4)" ::: "memory"); }     \
        __builtin_amdgcn_sched_barrier(0);                                    \
        _Pragma("unroll")                                                     \
        for (int nt = 0; nt < 2; ++nt) {                                      \
            o[0][nt] = MFMA16(va0, pb[nt].v, o[0][nt]);                       \
            o[1][nt] = MFMA16(va1, pb[nt].v, o[1][nt]);                       \
            o[2][nt] = MFMA16(va2, pb[nt].v, o[2][nt]);                       \
            o[3][nt] = MFMA16(va3, pb[nt].v, o[3][nt]);                       \
        }                                                                     \
    } while (0)

    gl16(kg,        lk0);        gl16(kg + 512,  lk0 + 512);
    gl16(kg + 1024, lk0 + 1024); gl16(kg + 1536, lk0 + 1536);

    for (int kt2 = 0; kt2 < 30; kt2 += 2) {
        ATTN_ITER(kt2,     lkr0, lk1, true, false);
        ATTN_ITER(kt2 + 1, lkr1, lk0, true, false);
    }
    ATTN_ITER(30, lkr0, lk1, true,  false);
    ATTN_ITER(31, lkr1, lk0, false, true);
#undef ATTN_ITER

#pragma unroll
    for (int nt = 0; nt < 2; ++nt) {
        l[nt] += __shfl_xor(l[nt], 16, 64);
        l[nt] += __shfl_xor(l[nt], 32, 64);
    }

    __syncthreads();
    if (quad == 0) {
#pragma unroll
        for (int nt = 0; nt < 2; ++nt)
            lbuf[wk * 64 + wq * 32 + nt * 16 + col] = l[nt];
    }
    __syncthreads();

    float scale[2];
#pragma unroll
    for (int nt = 0; nt < 2; ++nt) {
        const int ri = wq * 32 + nt * 16 + col;
        scale[nt] = 1.0f / (lbuf[ri] + lbuf[64 + ri]);
    }
#pragma unroll
    for (int dt = 0; dt < 4; ++dt)
#pragma unroll
        for (int nt = 0; nt < 2; ++nt) o[dt][nt] *= scale[nt];

    if (wk == 0) {
#pragma unroll
        for (int dt = 0; dt < 4; ++dt)
#pragma unroll
            for (int nt = 0; nt < 2; ++nt)
                *(f32x4*)&slab[(wq * 32 + nt * 16 + col) * 68 + dt * 16 + quad * 4] = o[dt][nt];
    }
    __syncthreads();
    if (wk == 1) {
#pragma unroll
        for (int dt = 0; dt < 4; ++dt)
#pragma unroll
            for (int nt = 0; nt < 2; ++nt) {
                f32x4* p = (f32x4*)&slab[(wq * 32 + nt * 16 + col) * 68 + dt * 16 + quad * 4];
                *p = *p + o[dt][nt];
            }
    }
    __syncthreads();

    const int qr = tid >> 2, fq = tid & 3;
#pragma unroll
    for (int j2 = 0; j2 < 4; ++j2) {
        const f32x4 a = *(const f32x4*)&slab[qr * 68 + fq * 16 + j2 * 4];
        *(f32x4*)&out[(size_t)(b * NS + q0 + qr) * ND + h * NDH + fq * 16 + j2 * 4] = a;
    }
}

extern "C" void kernel_launch(void* const* d_in, const int* in_sizes, int n_in,
                              void* d_out, int out_size, void* d_ws, size_t ws_size,
                              hipStream_t stream) {
    (void)in_sizes; (void)n_in; (void)out_size; (void)ws_size;
    const float* x  = (const float*)d_in[0];
    const float* wq = (const float*)d_in[1];
    const float* bq = (const float*)d_in[2];
    const float* wk = (const float*)d_in[3];
    const float* bk = (const float*)d_in[4];
    const float* wv = (const float*)d_in[5];
    const float* bv = (const float*)d_in[6];
    float* out = (float*)d_out;

    __bf16* qws  = (__bf16*)d_ws;
    __bf16* kws  = qws + (size_t)NB * NH * NS * NDH;
    __bf16* vtws = kws + (size_t)NB * NH * NS * NDH;

    proj_kernel<<<dim3(NS / 128, NH, NB), 256, 0, stream>>>(x, wq, bq, wk, bk, wv, bv, qws, kws, vtws);
    attn_kernel<<<dim3(NS / 64 * NH * NB), 256, 0, stream>>>(qws, kws, vtws, out);
}